// Round 6
// baseline (48.831 us; speedup 1.0000x reference)
//
#include <hip/hip_runtime.h>
#include <hip/hip_bf16.h>

// Problem constants (from reference)
#define T_LEN 2048
#define D_DIM 64
#define K_CH  8
#define B_SZ  8

// Chunked-scan config
#define CT 32                  // timesteps per chunk
#define NC (T_LEN / CT)        // 64 chunks per sequence
#define NBLK (B_SZ * NC)       // 512 blocks; launch_bounds(256,2) + no LDS
                               // -> 2 blocks/CU x 256 CU = all co-resident

typedef unsigned long long u64;
union F2U { float2 f; u64 u; };

__device__ __forceinline__ float2 cmul(float2 a, float2 b) {
    return make_float2(a.x * b.x - a.y * b.y, a.x * b.y + a.y * b.x);
}
__device__ __forceinline__ float2 cadd(float2 a, float2 b) {
    return make_float2(a.x + b.x, a.y + b.y);
}

// Single-launch fused chunked scan, wave-granular fence-free sync.
// Block bc=(b,c), 256 threads: k = tid>>5, d2 = tid&31 (2 d's per thread).
// A wave (64 lanes) spans two k channels; sync granularity = wave slice.
//  1. h chunk -> registers (reused for aggregate AND replay)
//  2. chunk aggregate S (even/odd A^2 chains for ILP)
//  3. publish S via device-scope relaxed atomic stores (write-through, no L2
//     flush), wave-local s_waitcnt vmcnt(0), then per-wave flag (relaxed
//     atomic). NO __threadfence, NO __syncthreads.
//  4. lanes poll predecessor flags (relaxed atomic loads), one acquire fence
//     (buffer_inv, no writeback), combine aggregates grouped by 4.
//  5. replay chunk from registers, coalesced float2 stores.
__global__ __launch_bounds__(256, 2) void s4d_onepass(
    const float* __restrict__ h,
    const float* __restrict__ log_neg_re,
    const float* __restrict__ imag,
    const float* __restrict__ B_proj,
    const float* __restrict__ log_dt,
    u64* __restrict__ agg,            // [NBLK][256][2] u64
    unsigned int* __restrict__ flags, // [NBLK][4], memset 0 each launch
    float* __restrict__ out)
{
    const int bc  = blockIdx.x;
    const int b   = bc / NC;
    const int c   = bc % NC;
    const int tid = threadIdx.x;
    const int k   = tid >> 5;
    const int d2  = tid & 31;
    const int wid = tid >> 6;
    const int lane = tid & 63;

    // --- per-k constants (closed form, matches reference) ---
    const float dt = expf(log_dt[0]);
    const float re = -expf(log_neg_re[k]);
    const float im = imag[k];
    const float mag = expf(re * dt);
    const float2 A  = make_float2(mag * cosf(im * dt), mag * sinf(im * dt));
    const float2 A2 = cmul(A, A);

    const float magC = expf(re * dt * (float)CT);
    const float angC = im * dt * (float)CT;
    const float2 Act  = make_float2(magC * cosf(angC), magC * sinf(angC));
    const float2 Act2 = cmul(Act, Act);
    const float2 Act3 = cmul(Act2, Act);
    const float2 Act4 = cmul(Act2, Act2);

    // C2 = 2 * B_proj * (A-1)/eig
    const float inv = 1.f / (re * re + im * im);
    const float2 num = make_float2(A.x - 1.f, A.y);
    const float bp = B_proj[k];
    const float2 C2v = make_float2(2.f * bp * (num.x * re + num.y * im) * inv,
                                   2.f * bp * (num.y * re - num.x * im) * inv);

    // --- 1. load chunk into registers ---
    const float2* hp = (const float2*)(h + ((size_t)b * T_LEN + (size_t)c * CT) * D_DIM) + d2;
    float2 hv[CT];
    #pragma unroll
    for (int t = 0; t < CT; ++t) hv[t] = hp[(size_t)t * (D_DIM / 2)];

    // --- 2. chunk aggregate: S = sum_t A^{CT-1-t} h_t  (even/odd split) ---
    float2 x0e = {0.f, 0.f}, x0o = {0.f, 0.f}, x1e = {0.f, 0.f}, x1o = {0.f, 0.f};
    #pragma unroll
    for (int m = 0; m < CT / 2; ++m) {
        x0e = cmul(A2, x0e); x0e.x += hv[2 * m].x;
        x1e = cmul(A2, x1e); x1e.x += hv[2 * m].y;
        x0o = cmul(A2, x0o); x0o.x += hv[2 * m + 1].x;
        x1o = cmul(A2, x1o); x1o.x += hv[2 * m + 1].y;
    }
    F2U s0; s0.f = cadd(cmul(A, x0e), x0o);
    F2U s1; s1.f = cadd(cmul(A, x1e), x1o);

    // --- 3. publish aggregate (device-scope write-through) + wave flag ---
    u64* ap = agg + ((size_t)bc * 256 + tid) * 2;
    __hip_atomic_store(&ap[0], s0.u, __ATOMIC_RELAXED, __HIP_MEMORY_SCOPE_AGENT);
    __hip_atomic_store(&ap[1], s1.u, __ATOMIC_RELAXED, __HIP_MEMORY_SCOPE_AGENT);
    asm volatile("s_waitcnt vmcnt(0)" ::: "memory");  // wave-local: all 64 lanes' stores acked
    if (lane == 0)
        __hip_atomic_store(&flags[bc * 4 + wid], 1u, __ATOMIC_RELAXED, __HIP_MEMORY_SCOPE_AGENT);

    // --- 4. wait for predecessors & combine their aggregates ---
    float2 x0 = {0.f, 0.f}, x1 = {0.f, 0.f};
    if (c > 0) {
        if (lane < c) {
            const unsigned int* fp = &flags[(b * NC + lane) * 4 + wid];
            while (__hip_atomic_load(fp, __ATOMIC_RELAXED, __HIP_MEMORY_SCOPE_AGENT) == 0u) { }
        }
        __builtin_amdgcn_fence(__ATOMIC_ACQUIRE, "agent");  // buffer_inv: no writeback

        const u64* cp = agg + ((size_t)(b * NC) * 256 + tid) * 2;
        const size_t cs = 256 * 2;  // u64 stride per predecessor chunk
        int j = 0;
        for (; j + 4 <= c; j += 4) {
            F2U a0, a1, a2, a3, b0, b1, b2, b3;
            a0.u = __hip_atomic_load(cp + (size_t)(j + 0) * cs,     __ATOMIC_RELAXED, __HIP_MEMORY_SCOPE_AGENT);
            b0.u = __hip_atomic_load(cp + (size_t)(j + 0) * cs + 1, __ATOMIC_RELAXED, __HIP_MEMORY_SCOPE_AGENT);
            a1.u = __hip_atomic_load(cp + (size_t)(j + 1) * cs,     __ATOMIC_RELAXED, __HIP_MEMORY_SCOPE_AGENT);
            b1.u = __hip_atomic_load(cp + (size_t)(j + 1) * cs + 1, __ATOMIC_RELAXED, __HIP_MEMORY_SCOPE_AGENT);
            a2.u = __hip_atomic_load(cp + (size_t)(j + 2) * cs,     __ATOMIC_RELAXED, __HIP_MEMORY_SCOPE_AGENT);
            b2.u = __hip_atomic_load(cp + (size_t)(j + 2) * cs + 1, __ATOMIC_RELAXED, __HIP_MEMORY_SCOPE_AGENT);
            a3.u = __hip_atomic_load(cp + (size_t)(j + 3) * cs,     __ATOMIC_RELAXED, __HIP_MEMORY_SCOPE_AGENT);
            b3.u = __hip_atomic_load(cp + (size_t)(j + 3) * cs + 1, __ATOMIC_RELAXED, __HIP_MEMORY_SCOPE_AGENT);
            float2 ta = cadd(cadd(cmul(Act3, a0.f), cmul(Act2, a1.f)),
                             cadd(cmul(Act,  a2.f), a3.f));
            x0 = cadd(cmul(Act4, x0), ta);
            float2 tb = cadd(cadd(cmul(Act3, b0.f), cmul(Act2, b1.f)),
                             cadd(cmul(Act,  b2.f), b3.f));
            x1 = cadd(cmul(Act4, x1), tb);
        }
        for (; j < c; ++j) {
            F2U a, bb;
            a.u  = __hip_atomic_load(cp + (size_t)j * cs,     __ATOMIC_RELAXED, __HIP_MEMORY_SCOPE_AGENT);
            bb.u = __hip_atomic_load(cp + (size_t)j * cs + 1, __ATOMIC_RELAXED, __HIP_MEMORY_SCOPE_AGENT);
            x0 = cadd(cmul(Act, x0), a.f);
            x1 = cadd(cmul(Act, x1), bb.f);
        }
    }

    // --- 5. replay chunk from registers, write output ---
    float2* op = (float2*)(out + (((size_t)b * T_LEN + (size_t)c * CT) * K_CH + k) * D_DIM) + d2;
    #pragma unroll
    for (int t = 0; t < CT; ++t) {
        x0 = cmul(A, x0); x0.x += hv[t].x;
        x1 = cmul(A, x1); x1.x += hv[t].y;
        op[(size_t)t * (K_CH * D_DIM / 2)] =
            make_float2(C2v.x * x0.x - C2v.y * x0.y,
                        C2v.x * x1.x - C2v.y * x1.y);   // 8B/lane coalesced
    }
}

extern "C" void kernel_launch(void* const* d_in, const int* in_sizes, int n_in,
                              void* d_out, int out_size, void* d_ws, size_t ws_size,
                              hipStream_t stream) {
    const float* h          = (const float*)d_in[0];
    const float* log_neg_re = (const float*)d_in[1];
    const float* imag       = (const float*)d_in[2];
    const float* B_proj     = (const float*)d_in[3];
    const float* log_dt     = (const float*)d_in[4];
    float* out = (float*)d_out;

    // d_ws layout: [0, 8KB) flags, [8KB, 8KB+2MB) aggregates
    unsigned int* flags = (unsigned int*)d_ws;
    u64*          agg   = (u64*)((char*)d_ws + 8192);

    // Flags must be 0 at kernel start every call (graph-capture-safe).
    hipMemsetAsync(flags, 0, NBLK * 4 * sizeof(unsigned int), stream);

    hipLaunchKernelGGL(s4d_onepass, dim3(NBLK), dim3(256), 0, stream,
                       h, log_neg_re, imag, B_proj, log_dt, agg, flags, out);
}

// Round 7
// 42.308 us; speedup vs baseline: 1.1542x; 1.1542x over previous
//
#include <hip/hip_runtime.h>
#include <hip/hip_bf16.h>

// Problem constants (from reference)
#define T_LEN 2048
#define D_DIM 64
#define K_CH  8
#define B_SZ  8

// Chunked-scan config
#define CT 32                  // timesteps per chunk
#define NC (T_LEN / CT)        // 64 chunks per sequence
#define NBLK (B_SZ * NC)       // 512 blocks; 256 thr, no LDS -> all co-resident

typedef unsigned long long u64;
union F2U { float2 f; u64 u; };

__device__ __forceinline__ float2 cmul(float2 a, float2 b) {
    return make_float2(a.x * b.x - a.y * b.y, a.x * b.y + a.y * b.x);
}
__device__ __forceinline__ float2 cadd(float2 a, float2 b) {
    return make_float2(a.x + b.x, a.y + b.y);
}

// Fused single-pass chunked scan, v3.
//  publish: relaxed agent atomic stores (write-through, cheap — R6-proven)
//  signal:  one atomicAdd per block on per-b counter (8 cachelines total)
//  wait:    single-thread spin w/ s_sleep backoff + one acquire fence/block
//  combine: NORMAL cached loads (L2/IF-served — fixes R6's uncached-read storm)
__global__ __launch_bounds__(256, 2) void s4d_fused3(
    const float* __restrict__ h,
    const float* __restrict__ log_neg_re,
    const float* __restrict__ imag,
    const float* __restrict__ B_proj,
    const float* __restrict__ log_dt,
    u64* __restrict__ agg,            // [NBLK][256][2]
    unsigned int* __restrict__ count, // [B_SZ] counters, 64-u32 (256B) spacing
    float* __restrict__ out)
{
    const int bc  = blockIdx.x;
    const int b   = bc / NC;
    const int c   = bc % NC;
    const int tid = threadIdx.x;
    const int k   = tid >> 5;
    const int d2  = tid & 31;

    // --- per-k constants (closed form, matches reference) ---
    const float dt = expf(log_dt[0]);
    const float re = -expf(log_neg_re[k]);
    const float im = imag[k];
    const float mag = expf(re * dt);
    const float2 A  = make_float2(mag * cosf(im * dt), mag * sinf(im * dt));
    const float2 A2 = cmul(A, A);

    const float magC = expf(re * dt * (float)CT);
    const float angC = im * dt * (float)CT;
    const float2 Act  = make_float2(magC * cosf(angC), magC * sinf(angC));
    const float2 Act2 = cmul(Act, Act);
    const float2 Act3 = cmul(Act2, Act);
    const float2 Act4 = cmul(Act2, Act2);

    // C2 = 2 * B_proj * (A-1)/eig
    const float inv = 1.f / (re * re + im * im);
    const float2 num = make_float2(A.x - 1.f, A.y);
    const float bp = B_proj[k];
    const float2 C2v = make_float2(2.f * bp * (num.x * re + num.y * im) * inv,
                                   2.f * bp * (num.y * re - num.x * im) * inv);

    // --- 1. load chunk into registers ---
    const float2* hp = (const float2*)(h + ((size_t)b * T_LEN + (size_t)c * CT) * D_DIM) + d2;
    float2 hv[CT];
    #pragma unroll
    for (int t = 0; t < CT; ++t) hv[t] = hp[(size_t)t * (D_DIM / 2)];

    // --- 2. chunk aggregate S = sum_t A^{CT-1-t} h_t (even/odd A^2 chains) ---
    float2 x0e = {0.f, 0.f}, x0o = {0.f, 0.f}, x1e = {0.f, 0.f}, x1o = {0.f, 0.f};
    #pragma unroll
    for (int m = 0; m < CT / 2; ++m) {
        x0e = cmul(A2, x0e); x0e.x += hv[2 * m].x;
        x1e = cmul(A2, x1e); x1e.x += hv[2 * m].y;
        x0o = cmul(A2, x0o); x0o.x += hv[2 * m + 1].x;
        x1o = cmul(A2, x1o); x1o.x += hv[2 * m + 1].y;
    }
    F2U s0; s0.f = cadd(cmul(A, x0e), x0o);
    F2U s1; s1.f = cadd(cmul(A, x1e), x1o);

    // --- 3. publish (write-through atomic stores), then one add per block ---
    u64* ap = agg + ((size_t)bc * 256 + tid) * 2;
    __hip_atomic_store(&ap[0], s0.u, __ATOMIC_RELAXED, __HIP_MEMORY_SCOPE_AGENT);
    __hip_atomic_store(&ap[1], s1.u, __ATOMIC_RELAXED, __HIP_MEMORY_SCOPE_AGENT);
    asm volatile("s_waitcnt vmcnt(0)" ::: "memory");  // lane's stores at coherence point
    __syncthreads();                                   // whole block's stores done
    if (tid == 0)
        __hip_atomic_fetch_add(&count[b * 64], 1u, __ATOMIC_RELAXED, __HIP_MEMORY_SCOPE_AGENT);

    // --- 4. wait for the c predecessors, then combine (cached loads) ---
    float2 x0 = {0.f, 0.f}, x1 = {0.f, 0.f};
    if (c > 0) {
        if (tid == 0) {
            while (__hip_atomic_load(&count[b * 64], __ATOMIC_RELAXED,
                                     __HIP_MEMORY_SCOPE_AGENT) < (unsigned)c)
                __builtin_amdgcn_s_sleep(1);
        }
        __syncthreads();
        __builtin_amdgcn_fence(__ATOMIC_ACQUIRE, "agent");  // buffer_inv; no writeback

        const float4* cp = (const float4*)(agg + ((size_t)(b * NC) * 256 + tid) * 2);
        const size_t cs = 256;  // float4 stride per predecessor chunk
        int j = 0;
        for (; j + 4 <= c; j += 4) {
            float4 s0v = cp[(size_t)(j + 0) * cs];
            float4 s1v = cp[(size_t)(j + 1) * cs];
            float4 s2v = cp[(size_t)(j + 2) * cs];
            float4 s3v = cp[(size_t)(j + 3) * cs];
            float2 ta = cadd(cadd(cmul(Act3, make_float2(s0v.x, s0v.y)),
                                  cmul(Act2, make_float2(s1v.x, s1v.y))),
                             cadd(cmul(Act,  make_float2(s2v.x, s2v.y)),
                                  make_float2(s3v.x, s3v.y)));
            x0 = cadd(cmul(Act4, x0), ta);
            float2 tb = cadd(cadd(cmul(Act3, make_float2(s0v.z, s0v.w)),
                                  cmul(Act2, make_float2(s1v.z, s1v.w))),
                             cadd(cmul(Act,  make_float2(s2v.z, s2v.w)),
                                  make_float2(s3v.z, s3v.w)));
            x1 = cadd(cmul(Act4, x1), tb);
        }
        for (; j < c; ++j) {
            float4 sv = cp[(size_t)j * cs];
            x0 = cadd(cmul(Act, x0), make_float2(sv.x, sv.y));
            x1 = cadd(cmul(Act, x1), make_float2(sv.z, sv.w));
        }
    }

    // --- 5. replay chunk from registers, coalesced float2 stores ---
    float2* op = (float2*)(out + (((size_t)b * T_LEN + (size_t)c * CT) * K_CH + k) * D_DIM) + d2;
    #pragma unroll
    for (int t = 0; t < CT; ++t) {
        x0 = cmul(A, x0); x0.x += hv[t].x;
        x1 = cmul(A, x1); x1.x += hv[t].y;
        op[(size_t)t * (K_CH * D_DIM / 2)] =
            make_float2(C2v.x * x0.x - C2v.y * x0.y,
                        C2v.x * x1.x - C2v.y * x1.y);
    }
}

extern "C" void kernel_launch(void* const* d_in, const int* in_sizes, int n_in,
                              void* d_out, int out_size, void* d_ws, size_t ws_size,
                              hipStream_t stream) {
    const float* h          = (const float*)d_in[0];
    const float* log_neg_re = (const float*)d_in[1];
    const float* imag       = (const float*)d_in[2];
    const float* B_proj     = (const float*)d_in[3];
    const float* log_dt     = (const float*)d_in[4];
    float* out = (float*)d_out;

    // d_ws: [0, 2KB) per-b counters (256B spacing), [8KB, 8KB+2MB) aggregates
    unsigned int* count = (unsigned int*)d_ws;
    u64*          agg   = (u64*)((char*)d_ws + 8192);

    // Counters must start at 0 every call (graph-capture-safe).
    hipMemsetAsync(count, 0, B_SZ * 64 * sizeof(unsigned int), stream);

    hipLaunchKernelGGL(s4d_fused3, dim3(NBLK), dim3(256), 0, stream,
                       h, log_neg_re, imag, B_proj, log_dt, agg, count, out);
}

// Round 8
// 29.382 us; speedup vs baseline: 1.6620x; 1.4399x over previous
//
#include <hip/hip_runtime.h>
#include <hip/hip_bf16.h>

// Problem constants (from reference)
#define T_LEN 2048
#define D_DIM 64
#define K_CH  8
#define B_SZ  8

// Chunked-scan config: CT=64 -> NC=32 -> 256 blocks (1/CU), 4x less combine
// traffic than CT=32 (sum_c c * 4KB * B = 16 MB vs 64 MB).
#define CT 64
#define NC (T_LEN / CT)        // 32 chunks
#define NBLK (B_SZ * NC)       // 256 blocks

__device__ __forceinline__ float2 cmul(float2 a, float2 b) {
    return make_float2(a.x * b.x - a.y * b.y, a.x * b.y + a.y * b.x);
}
__device__ __forceinline__ float2 cadd(float2 a, float2 b) {
    return make_float2(a.x + b.x, a.y + b.y);
}

// Block mapping (both kernels): b = bid & 7, c = bid >> 3.
// With round-robin XCD placement this pins each sequence b to one XCD, so
// h[b] (512 KB) and carries[b] (128 KB) stay L2-local between the two
// dispatches. Perf heuristic only — correctness comes from the kernel
// boundary (G16-safe).

// Kernel 1: chunk-local aggregate S = sum_j A^{CT-1-j} h[j] (zero init),
// even/odd A^2 chains for ILP. 512 threads = k(8) x d(64).
__global__ __launch_bounds__(512) void s4d_carry(
    const float* __restrict__ h,
    const float* __restrict__ log_neg_re,
    const float* __restrict__ imag,
    const float* __restrict__ log_dt,
    float2* __restrict__ carries)   // [B][NC][K][D] complex
{
    const int bid = blockIdx.x;
    const int b = bid & 7;
    const int c = bid >> 3;
    const int tid = threadIdx.x;    // 0..511
    const int k = tid >> 6;         // wave-uniform
    const int d = tid & 63;

    const float dt = expf(log_dt[0]);
    const float re = -expf(log_neg_re[k]);
    const float im = imag[k];
    const float mag = expf(re * dt);
    const float2 A  = make_float2(mag * cosf(im * dt), mag * sinf(im * dt));
    const float2 A2 = cmul(A, A);

    const float* hp = h + ((size_t)b * T_LEN + (size_t)c * CT) * D_DIM + d;

    float2 se = {0.f, 0.f}, so = {0.f, 0.f};
    #pragma unroll 8
    for (int m = 0; m < CT / 2; ++m) {
        float he = hp[(size_t)(2 * m) * D_DIM];       // 256B/wave coalesced
        float ho = hp[(size_t)(2 * m + 1) * D_DIM];
        se = cmul(A2, se); se.x += he;
        so = cmul(A2, so); so.x += ho;
    }
    const float2 S = cadd(cmul(A, se), so);

    carries[((size_t)(b * NC + c) * K_CH + k) * D_DIM + d] = S;  // 512B/wave
}

// Kernel 2: combine predecessor carries (grouped by 4, software-pipelined
// register prefetch to hide L2/L3 latency), then replay chunk, write out.
__global__ __launch_bounds__(512) void s4d_out(
    const float* __restrict__ h,
    const float* __restrict__ log_neg_re,
    const float* __restrict__ imag,
    const float* __restrict__ B_proj,
    const float* __restrict__ log_dt,
    const float2* __restrict__ carries,
    float* __restrict__ out)
{
    const int bid = blockIdx.x;
    const int b = bid & 7;
    const int c = bid >> 3;
    const int tid = threadIdx.x;
    const int k = tid >> 6;
    const int d = tid & 63;

    const float dt = expf(log_dt[0]);
    const float re = -expf(log_neg_re[k]);
    const float im = imag[k];
    const float mag = expf(re * dt);
    const float2 A = make_float2(mag * cosf(im * dt), mag * sinf(im * dt));

    const float magC = expf(re * dt * (float)CT);
    const float angC = im * dt * (float)CT;
    const float2 Act  = make_float2(magC * cosf(angC), magC * sinf(angC));
    const float2 Act2 = cmul(Act, Act);
    const float2 Act3 = cmul(Act2, Act);
    const float2 Act4 = cmul(Act2, Act2);

    // C2 = 2 * B_proj * (A-1)/eig
    const float inv = 1.f / (re * re + im * im);
    const float2 num = make_float2(A.x - 1.f, A.y);
    const float bp = B_proj[k];
    const float2 C2v = make_float2(2.f * bp * (num.x * re + num.y * im) * inv,
                                   2.f * bp * (num.y * re - num.x * im) * inv);

    // ---- issue h loads early: HBM latency hides under the combine ----
    const float* hp = h + ((size_t)b * T_LEN + (size_t)c * CT) * D_DIM + d;
    float hv[CT];
    #pragma unroll
    for (int t = 0; t < CT; ++t) hv[t] = hp[(size_t)t * D_DIM];

    // ---- combine carries of chunks 0..c-1, grouped by 4, prefetched ----
    const float2* cp = carries + ((size_t)(b * NC) * K_CH + (size_t)k) * D_DIM + d;
    const size_t cs = (size_t)K_CH * D_DIM;   // stride between chunks
    float2 x = {0.f, 0.f};
    {
        const int ng = c >> 2;       // full groups of 4
        float2 g0, g1, g2, g3, n0, n1, n2, n3;
        if (ng > 0) {
            g0 = cp[0 * cs]; g1 = cp[1 * cs]; g2 = cp[2 * cs]; g3 = cp[3 * cs];
        }
        for (int gi = 0; gi < ng; ++gi) {
            const int jn = (gi + 1) << 2;
            if (gi + 1 < ng) {       // prefetch next group while combining
                n0 = cp[(size_t)(jn + 0) * cs];
                n1 = cp[(size_t)(jn + 1) * cs];
                n2 = cp[(size_t)(jn + 2) * cs];
                n3 = cp[(size_t)(jn + 3) * cs];
            }
            float2 t01 = cadd(cmul(Act3, g0), cmul(Act2, g1));
            float2 t23 = cadd(cmul(Act, g2), g3);
            x = cadd(cmul(Act4, x), cadd(t01, t23));
            g0 = n0; g1 = n1; g2 = n2; g3 = n3;
        }
        for (int j = ng << 2; j < c; ++j) {
            float2 s = cp[(size_t)j * cs];
            x = cadd(cmul(Act, x), s);
        }
    }

    // ---- replay chunk from registers, coalesced 256B/wave stores ----
    float* op = out + (((size_t)b * T_LEN + (size_t)c * CT) * K_CH + k) * D_DIM + d;
    #pragma unroll 8
    for (int t = 0; t < CT; ++t) {
        x = cmul(A, x);
        x.x += hv[t];
        op[(size_t)t * (K_CH * D_DIM)] = C2v.x * x.x - C2v.y * x.y;
    }
}

extern "C" void kernel_launch(void* const* d_in, const int* in_sizes, int n_in,
                              void* d_out, int out_size, void* d_ws, size_t ws_size,
                              hipStream_t stream) {
    const float* h          = (const float*)d_in[0];
    const float* log_neg_re = (const float*)d_in[1];
    const float* imag       = (const float*)d_in[2];
    const float* B_proj     = (const float*)d_in[3];
    const float* log_dt     = (const float*)d_in[4];
    float* out = (float*)d_out;

    float2* carries = (float2*)d_ws;   // 8*32*8*64*8B = 1 MiB

    hipLaunchKernelGGL(s4d_carry, dim3(NBLK), dim3(512), 0, stream,
                       h, log_neg_re, imag, log_dt, carries);
    hipLaunchKernelGGL(s4d_out, dim3(NBLK), dim3(512), 0, stream,
                       h, log_neg_re, imag, B_proj, log_dt, carries, out);
}

// Round 9
// 20.671 us; speedup vs baseline: 2.3623x; 1.4214x over previous
//
#include <hip/hip_runtime.h>
#include <hip/hip_bf16.h>

// Problem constants (from reference)
#define T_LEN 2048
#define D_DIM 64
#define K_CH  8
#define B_SZ  8

// Chunked-scan config: CT=64 -> NC=32 -> 256 blocks, 512 threads.
#define CT 64
#define NC (T_LEN / CT)        // 32 chunks
#define NBLK (B_SZ * NC)       // 256 blocks

__device__ __forceinline__ float2 cmul(float2 a, float2 b) {
    return make_float2(a.x * b.x - a.y * b.y, a.x * b.y + a.y * b.x);
}
__device__ __forceinline__ float2 cadd(float2 a, float2 b) {
    return make_float2(a.x + b.x, a.y + b.y);
}

// Kernel 1: chunk-local aggregate S = sum_j A^{CT-1-j} h[j] (zero init),
// even/odd A^2 chains for ILP. 512 threads = k(8) x d(64).
__global__ __launch_bounds__(512) void s4d_carry(
    const float* __restrict__ h,
    const float* __restrict__ log_neg_re,
    const float* __restrict__ imag,
    const float* __restrict__ log_dt,
    float2* __restrict__ carries)   // [B][NC][K][D] complex
{
    const int bid = blockIdx.x;
    const int b = bid / NC;
    const int c = bid % NC;
    const int tid = threadIdx.x;    // 0..511
    const int k = tid >> 6;         // wave-uniform
    const int d = tid & 63;

    const float dt = expf(log_dt[0]);
    const float re = -expf(log_neg_re[k]);
    const float im = imag[k];
    const float mag = expf(re * dt);
    const float2 A  = make_float2(mag * cosf(im * dt), mag * sinf(im * dt));
    const float2 A2 = cmul(A, A);

    const float* hp = h + ((size_t)b * T_LEN + (size_t)c * CT) * D_DIM + d;

    float2 se = {0.f, 0.f}, so = {0.f, 0.f};
    #pragma unroll 8
    for (int m = 0; m < CT / 2; ++m) {
        float he = hp[(size_t)(2 * m) * D_DIM];       // 256B/wave coalesced
        float ho = hp[(size_t)(2 * m + 1) * D_DIM];
        se = cmul(A2, se); se.x += he;
        so = cmul(A2, so); so.x += ho;
    }
    const float2 S = cadd(cmul(A, se), so);

    carries[((size_t)(b * NC + c) * K_CH + k) * D_DIM + d] = S;
}

// Kernel 2: issue ALL predecessor-carry loads up front (fully unrolled,
// statically indexed, uniform-predicated -> all overlap in the memory
// pipeline; exposed latency ~= one L3 round trip), Horner-combine from
// registers, then replay the chunk streaming h, coalesced stores.
__global__ __launch_bounds__(512) void s4d_out(
    const float* __restrict__ h,
    const float* __restrict__ log_neg_re,
    const float* __restrict__ imag,
    const float* __restrict__ B_proj,
    const float* __restrict__ log_dt,
    const float2* __restrict__ carries,
    float* __restrict__ out)
{
    const int bid = blockIdx.x;
    const int b = bid / NC;
    const int c = bid % NC;      // block-uniform
    const int tid = threadIdx.x;
    const int k = tid >> 6;
    const int d = tid & 63;

    const float dt = expf(log_dt[0]);
    const float re = -expf(log_neg_re[k]);
    const float im = imag[k];
    const float mag = expf(re * dt);
    const float2 A = make_float2(mag * cosf(im * dt), mag * sinf(im * dt));

    const float magC = expf(re * dt * (float)CT);
    const float angC = im * dt * (float)CT;
    const float2 Act = make_float2(magC * cosf(angC), magC * sinf(angC));

    // C2 = 2 * B_proj * (A-1)/eig
    const float inv = 1.f / (re * re + im * im);
    const float2 num = make_float2(A.x - 1.f, A.y);
    const float bp = B_proj[k];
    const float2 C2v = make_float2(2.f * bp * (num.x * re + num.y * im) * inv,
                                   2.f * bp * (num.y * re - num.x * im) * inv);

    // ---- combine: issue all c loads, then Horner from registers ----
    // x_init = sum_{j<c} Act^{c-1-j} S_j
    const float2* cp = carries + ((size_t)(b * NC) * K_CH + (size_t)k) * D_DIM + d;
    const size_t cs = (size_t)K_CH * D_DIM;   // chunk stride in float2

    float2 sv[NC - 1];
    #pragma unroll
    for (int j = 0; j < NC - 1; ++j) {
        // j < c is block-uniform; all sv[] indices compile-time (rule #20)
        sv[j] = (j < c) ? cp[(size_t)j * cs] : make_float2(0.f, 0.f);
    }
    float2 x = {0.f, 0.f};
    #pragma unroll
    for (int j = 0; j < NC - 1; ++j) {
        if (j < c) x = cadd(cmul(Act, x), sv[j]);   // uniform guard, static idx
    }

    // ---- replay chunk streaming h, coalesced 256B/wave stores ----
    const float* hp = h + ((size_t)b * T_LEN + (size_t)c * CT) * D_DIM + d;
    float* op = out + (((size_t)b * T_LEN + (size_t)c * CT) * K_CH + k) * D_DIM + d;

    #pragma unroll 8
    for (int t = 0; t < CT; ++t) {
        float hv = hp[(size_t)t * D_DIM];
        x = cmul(A, x);
        x.x += hv;
        op[(size_t)t * (K_CH * D_DIM)] = C2v.x * x.x - C2v.y * x.y;
    }
}

extern "C" void kernel_launch(void* const* d_in, const int* in_sizes, int n_in,
                              void* d_out, int out_size, void* d_ws, size_t ws_size,
                              hipStream_t stream) {
    const float* h          = (const float*)d_in[0];
    const float* log_neg_re = (const float*)d_in[1];
    const float* imag       = (const float*)d_in[2];
    const float* B_proj     = (const float*)d_in[3];
    const float* log_dt     = (const float*)d_in[4];
    float* out = (float*)d_out;

    float2* carries = (float2*)d_ws;   // 8*32*8*64*8B = 1 MiB

    hipLaunchKernelGGL(s4d_carry, dim3(NBLK), dim3(512), 0, stream,
                       h, log_neg_re, imag, log_dt, carries);
    hipLaunchKernelGGL(s4d_out, dim3(NBLK), dim3(512), 0, stream,
                       h, log_neg_re, imag, B_proj, log_dt, carries, out);
}